// Round 1
// baseline (1513.326 us; speedup 1.0000x reference)
//
#include <hip/hip_runtime.h>
#include <cstdint>
#include <cstddef>

// EEG_SimpleLSM: 3-layer LIF + winner-take-all spiking net, T=4000 serial scan.
// One wave (64 lanes) per batch sample. s0/s1 are one-hot -> W@s is a column
// gather from LDS (padded rows => conflict-free). Argmax via DPP max-reduce +
// ballot/ffs (first-index tie-break == jnp.argmax). Layers skewed by one step
// each (L2(t-2); L1(t-1); L0(t)) so loop-carried chains are short and the
// W-column LDS gather has a full iteration of latency slack.

constexpr int T_TOTAL = 4000;
constexpr int NCH = 32;            // input channels / layer-0 neurons
constexpr int N1 = 64;             // layer-1 neurons
constexpr int N2 = 128;            // layer-2 neurons
constexpr int CT = 64;             // time-steps per LDS x-chunk
constexpr int XS_STRIDE = NCH + 1; // pad -> conflict-free xs reads

template <int CTRL>
__device__ __forceinline__ float dpp_max(float v) {
  int iv = __builtin_bit_cast(int, v);
  // old = self, bound_ctrl=false: invalid source lanes keep current value,
  // so the reduction is exact (no injected zeros).
  int sh = __builtin_amdgcn_update_dpp(iv, iv, CTRL, 0xF, 0xF, false);
  return fmaxf(v, __builtin_bit_cast(float, sh));
}

__device__ __forceinline__ float read_lane_f(float v, int lane) {
  return __builtin_bit_cast(float, __builtin_amdgcn_readlane(__builtin_bit_cast(int, v), lane));
}

__global__ __launch_bounds__(64, 1) void lsm_kernel(
    const float* __restrict__ x, const float* __restrict__ W1,
    const float* __restrict__ W2, float* __restrict__ out) {
  __shared__ float w1s[N1 * 33];  // W1[64][32] with stride 33: gather is conflict-free
  __shared__ float w2s[N2 * 65];  // W2[128][64] with stride 65
  __shared__ float xs[CT * XS_STRIDE];  // transposed chunk: xs[t][c]

  const int lane = threadIdx.x;
  const int b = blockIdx.x;

  // Stage weights (single wave per block: in-wave DS ordering, no barrier needed).
  for (int e = lane; e < N1 * NCH; e += 64) w1s[(e >> 5) * 33 + (e & 31)] = W1[e];
  for (int e = lane; e < N2 * N1; e += 64) w2s[(e >> 6) * 65 + (e & 63)] = W2[e];

  const float* xb = x + (size_t)b * (NCH * T_TOTAL);

  // State. Lanes >=32 keep v0 == 0 forever (xt forced 0): harmless for the
  // 32-lane reduction (read from lane 31) and for reset (0 < 1.5).
  float v0 = 0.f, v1 = 0.f, v2a = 0.f, v2b = 0.f;
  float pv2a = 0.f, pv2b = 0.f;          // pre-reset membrane of layer 2
  float h1p = 0.f, h2ap = 0.f, h2bp = 0.f;  // prefetched W columns
  bool f0 = false, f1 = false;

  const int w1base = lane * 33;
  const int w2base_a = lane * 65;
  const int w2base_b = (lane + 64) * 65;

  // Prefetch chunk 0 into registers (32 VGPRs).
  float xpre[NCH];
#pragma unroll
  for (int k = 0; k < NCH; ++k) xpre[k] = xb[k * T_TOTAL + lane];

  // ---- layer bodies (skewed consumers of previous iteration's f/j/h) ----
  auto do_l2 = [&]() {  // time t-2, consumes f1 + prefetched W2 column
    float da = v2a * (1.0f / 80000.0f);
    float db = v2b * (1.0f / 80000.0f);
    if (f1) {
      float pa = (v2a + h2ap) - da;
      float pb = (v2b + h2bp) - db;
      pv2a = pa; pv2b = pb;
      v2a = (pa >= 1.2f) ? 0.f : pa;
      v2b = (pb >= 1.2f) ? 0.f : pb;
    } else {  // no charge => all < 1.2 stays < 1.2 under decay: reset is a no-op
      float pa = v2a - da;
      float pb = v2b - db;
      pv2a = pa; pv2b = pb;
      v2a = pa; v2b = pb;
    }
  };

  auto do_l1 = [&]() {  // time t-1, consumes f0 + prefetched W1 column
    float d = v1 * (1.0f / 80000.0f);
    if (f0) {
      float nv = (v1 + h1p) - d;
      float m = nv;
      m = dpp_max<0x111>(m); m = dpp_max<0x112>(m); m = dpp_max<0x114>(m);
      m = dpp_max<0x118>(m); m = dpp_max<0x142>(m); m = dpp_max<0x143>(m);
      float m1 = read_lane_f(m, 63);
      f1 = (m1 >= 1.2f);
      if (f1) {
        unsigned long long bal = __ballot(nv == m1);
        int j1 = __ffsll(bal) - 1;  // lowest index among ties == jnp.argmax
        h2ap = w2s[w2base_a + j1];  // prefetch for next iteration's L2
        h2bp = w2s[w2base_b + j1];
        nv = (nv >= 1.2f) ? 0.f : nv;
      }
      v1 = nv;
    } else {  // spike impossible without charge (invariant: all v1 < 1.2)
      v1 = v1 - d;
      f1 = false;
    }
  };

  auto do_l0 = [&](float xt) {  // time t
    float d = v0 / 3.0f;  // IEEE div: bit-exact vs reference fp32
    float nv = (v0 + xt) - d;
    float m = nv;
    m = dpp_max<0x111>(m); m = dpp_max<0x112>(m); m = dpp_max<0x114>(m);
    m = dpp_max<0x118>(m); m = dpp_max<0x142>(m);
    float m0 = read_lane_f(m, 31);  // max over lanes 0..31
    f0 = (m0 >= 1.5f);
    if (f0) {
      unsigned long long bal = __ballot(nv == m0) & 0xFFFFFFFFull;
      int j0 = __ffsll(bal) - 1;
      h1p = w1s[w1base + j0];  // prefetch for next iteration's L1
    }
    v0 = (nv >= 1.5f) ? 0.f : nv;
  };

  const int nchunks = (T_TOTAL + CT - 1) / CT;  // 63 (last chunk = 32 steps)
  for (int c0 = 0; c0 < nchunks; ++c0) {
    // Commit prefetched chunk to LDS, transposed: value(ch k, time lane).
#pragma unroll
    for (int k = 0; k < NCH; ++k) xs[lane * XS_STRIDE + k] = xpre[k];
    // Kick off next chunk's global loads (latency covered by ~64 steps of compute).
    const int t0n = (c0 + 1) * CT;
    if (t0n < T_TOTAL) {
      const int tg = t0n + lane;
      const bool ok = (tg < T_TOTAL);
#pragma unroll
      for (int k = 0; k < NCH; ++k) xpre[k] = ok ? xb[k * T_TOTAL + tg] : 0.f;
    }
    const int steps = min(CT, T_TOTAL - c0 * CT);
    for (int tt = 0; tt < steps; ++tt) {
      float xt = 0.f;
      if (lane < NCH) xt = xs[tt * XS_STRIDE + lane];  // issued early, used last
      do_l2();   // time t-2 (ghost on zero state for t<2: exact no-op)
      do_l1();   // time t-1 (ghost for t<1)
      do_l0(xt); // time t
    }
  }
  // Drain the skew: L2(3998), L1(3999), L2(3999).
  do_l2();
  do_l1();
  do_l2();

  out[(size_t)b * N2 + lane] = expf(pv2a);
  out[(size_t)b * N2 + 64 + lane] = expf(pv2b);
}

extern "C" void kernel_launch(void* const* d_in, const int* in_sizes, int n_in,
                              void* d_out, int out_size, void* d_ws, size_t ws_size,
                              hipStream_t stream) {
  (void)n_in; (void)out_size; (void)d_ws; (void)ws_size;
  const float* x = (const float*)d_in[0];
  const float* W1 = (const float*)d_in[1];
  const float* W2 = (const float*)d_in[2];
  float* out = (float*)d_out;
  const int B = in_sizes[0] / (NCH * T_TOTAL);  // 256
  lsm_kernel<<<dim3(B), dim3(64), 0, stream>>>(x, W1, W2, out);
}

// Round 2
// 1069.181 us; speedup vs baseline: 1.4154x; 1.4154x over previous
//
#include <hip/hip_runtime.h>
#include <cstdint>
#include <cstddef>

// EEG_SimpleLSM: 3-layer LIF + WTA spiking net, T=4000 serial scan.
// One wave per sample (256 waves on 256 CUs): wall time == one sample's
// serial chain, so everything below targets per-step critical-path latency.
//  - Fully branchless step (exact: reference always charges with h=0 and
//    always applies the unmasked reset; select via exact *1.0/*0.0 mul).
//  - Body order L0(t), L2(t-2), L1(t-1): the W1-column LDS gather gets ~1.5
//    iterations of slack, W2 gather ~1 iteration (LDS latency ~120 cyc).
//  - v0's /3.0 div moved off the loop-carried chain (reset needs only the
//    per-lane compare; div result consumed next iteration).
//  - xt prefetched one step ahead (register ping-pong).
// #pragma fp contract(off): match numpy's separate-rounding of v - v/tau.

#pragma clang fp contract(off)

constexpr int T_TOTAL = 4000;
constexpr int NCH = 32;
constexpr int N1 = 64;
constexpr int N2 = 128;
constexpr int CT = 64;
constexpr int XSS = NCH + 1;

template <int CTRL>
__device__ __forceinline__ float dpp_max(float v) {
  int iv = __builtin_bit_cast(int, v);
  // old=self, bound_ctrl=false: invalid lanes keep old value -> exact reduce.
  int sh = __builtin_amdgcn_update_dpp(iv, iv, CTRL, 0xF, 0xF, false);
  return fmaxf(v, __builtin_bit_cast(float, sh));
}
__device__ __forceinline__ float read_lane_f(float v, int lane) {
  return __builtin_bit_cast(float, __builtin_amdgcn_readlane(__builtin_bit_cast(int, v), lane));
}

__global__ __launch_bounds__(64, 1) void lsm_kernel(
    const float* __restrict__ x, const float* __restrict__ W1,
    const float* __restrict__ W2, float* __restrict__ out) {
  __shared__ float w1s[N1 * 33];       // stride 33: column gather conflict-free
  __shared__ float w2s[N2 * 65];       // stride 65
  __shared__ float xs[CT * XSS];       // transposed x chunk: xs[t][c]

  const int lane = threadIdx.x;
  const int b = blockIdx.x;

  // Stage weights (single wave: in-wave DS ordering, no barrier needed).
  for (int e = lane; e < N1 * NCH; e += 64) w1s[(e >> 5) * 33 + (e & 31)] = W1[e];
  for (int e = lane; e < N2 * N1; e += 64) w2s[(e >> 6) * 65 + (e & 63)] = W2[e];

  const float* xb = x + (size_t)b * (NCH * T_TOTAL);

  // State. Lanes 32-63 mirror lanes 0-31 for L0 (xt read with lane&31):
  // harmless — the 32-lane reduce reads lane 31 (row_shr/bcast15 never pull
  // from lanes>=32), and ballot's ffs picks the lowest (real) lane.
  float v0 = 0.f, d0 = 0.f, v1 = 0.f, v2a = 0.f, v2b = 0.f;
  float pv2a = 0.f, pv2b = 0.f;
  // pipeline regs: L0->L1 is double-buffered (produced body1 iter i,
  // consumed body3 iter i+1); L1->L2 single (read in body2 before body3 writes).
  float h1rA = 0.f, i0A = 0.f, h1rB = 0.f, i0B = 0.f;
  float h2ra = 0.f, h2rb = 0.f, i1 = 0.f;

  const int w1base = lane * 33;
  const int w2ba = lane * 65;
  const int w2bb = (lane + 64) * 65;
  const int xlane = lane & 31;

  float xpre[NCH];
#pragma unroll
  for (int k = 0; k < NCH; ++k) xpre[k] = xb[k * T_TOTAL + lane];

  float xt_cur = 0.f, xt_nxt = 0.f;

  auto l2_once = [&]() {  // time t-2: consume h2ra/h2rb/i1
    float h2a = h2ra * i1;                   // exact (*1 or *0)
    float h2b = h2rb * i1;
    float pa = (v2a + h2a) - v2a * (1.0f / 80000.0f);
    float pb = (v2b + h2b) - v2b * (1.0f / 80000.0f);
    pv2a = pa; pv2b = pb;
    v2a = (pa >= 1.2f) ? 0.f : pa;           // unmasked reset == reference
    v2b = (pb >= 1.2f) ? 0.f : pb;
  };

  auto l1_once = [&](float h1in, float i0in) {  // time t-1: consume h1/i0
    float h1 = h1in * i0in;                  // exact
    float nv1 = (v1 + h1) - v1 * (1.0f / 80000.0f);
    v1 = (nv1 >= 1.2f) ? 0.f : nv1;
    float n = nv1;
    n = dpp_max<0x111>(n); n = dpp_max<0x112>(n); n = dpp_max<0x114>(n);
    n = dpp_max<0x118>(n); n = dpp_max<0x142>(n); n = dpp_max<0x143>(n);
    float m1 = read_lane_f(n, 63);
    i1 = (m1 >= 1.2f) ? 1.0f : 0.0f;
    unsigned long long bal1 = __ballot(nv1 == m1);
    int j1 = __ffsll(bal1) - 1;              // first-index tie-break == argmax
    h2ra = w2s[w2ba + j1];                   // consumed next iteration's L2
    h2rb = w2s[w2bb + j1];
  };

  int steps = CT;

  auto lif_step = [&](int tt, float h1in, float i0in, float& h1out, float& i0out) {
    // prefetch next xt (full step of slack before its use)
    int nidx = tt + 1; if (nidx >= steps) nidx = steps - 1;
    xt_nxt = xs[nidx * XSS + xlane];
    // ---- L0(t) ----
    float nv0 = (v0 + xt_cur) - d0;
    v0 = (nv0 >= 1.5f) ? 0.f : nv0;          // per-lane reset, no reduce needed
    d0 = v0 / 3.0f;                          // off the chain: used next iter
    float m = nv0;
    m = dpp_max<0x111>(m); m = dpp_max<0x112>(m); m = dpp_max<0x114>(m);
    m = dpp_max<0x118>(m); m = dpp_max<0x142>(m);
    float m0 = read_lane_f(m, 31);
    i0out = (m0 >= 1.5f) ? 1.0f : 0.0f;
    unsigned long long bal0 = __ballot(nv0 == m0);
    int j0 = __ffsll(bal0) - 1;              // always a lane <32 (ffs = lowest)
    h1out = w1s[w1base + j0];                // consumed next iteration's L1
    // ---- L2(t-2), L1(t-1) ----
    l2_once();
    l1_once(h1in, i0in);
    xt_cur = xt_nxt;
  };

  const int nchunks = (T_TOTAL + CT - 1) / CT;  // 63 (last = 32 steps, even)
  for (int c0 = 0; c0 < nchunks; ++c0) {
    // Commit prefetched chunk to LDS transposed; reads below are in-wave ordered.
#pragma unroll
    for (int k = 0; k < NCH; ++k) xs[lane * XSS + k] = xpre[k];
    const int t0n = (c0 + 1) * CT;
    if (t0n < T_TOTAL) {
      const int tg = t0n + lane;
      const bool ok = tg < T_TOTAL;
#pragma unroll
      for (int k = 0; k < NCH; ++k) xpre[k] = ok ? xb[k * T_TOTAL + tg] : 0.f;
    }
    steps = min(CT, T_TOTAL - c0 * CT);
    xt_cur = xs[xlane];                      // row 0 of this chunk
    for (int tt = 0; tt < steps; tt += 2) {  // steps always even
      lif_step(tt, h1rA, i0A, h1rB, i0B);
      lif_step(tt + 1, h1rB, i0B, h1rA, i0A);
    }
  }
  // Drain the skew. t=3999 (odd) wrote slot A.
  l2_once();                // L2(3998)
  l1_once(h1rA, i0A);       // L1(3999)
  l2_once();                // L2(3999) -> final pv2
  out[(size_t)b * N2 + lane] = expf(pv2a);
  out[(size_t)b * N2 + 64 + lane] = expf(pv2b);
}

extern "C" void kernel_launch(void* const* d_in, const int* in_sizes, int n_in,
                              void* d_out, int out_size, void* d_ws, size_t ws_size,
                              hipStream_t stream) {
  (void)n_in; (void)out_size; (void)d_ws; (void)ws_size;
  const float* x = (const float*)d_in[0];
  const float* W1 = (const float*)d_in[1];
  const float* W2 = (const float*)d_in[2];
  float* out = (float*)d_out;
  const int B = in_sizes[0] / (NCH * T_TOTAL);  // 256
  lsm_kernel<<<dim3(B), dim3(64), 0, stream>>>(x, W1, W2, out);
}

// Round 3
// 1014.321 us; speedup vs baseline: 1.4920x; 1.0541x over previous
//
#include <hip/hip_runtime.h>
#include <cstdint>
#include <cstddef>

// EEG_SimpleLSM: 3-layer LIF + WTA spiking net, T=4000 serial scan.
// One wave per sample (256 waves = 1/CU): wall time == one sample's serial
// chain. Round-3 structure: deep software pipeline, body k (2 steps) runs
//   L2(t-4,t-3) -> L1(t-2,t-1) -> L0(t,t+1)
// so every cross-layer hand-off (j0 -> W1 LDS gather -> L1; j1 -> W2 gather
// -> L2; i-flags) is produced in body k and consumed in body k+1: the
// ~190-cyc DPP-reduce+LDS-gather chains get a full ~2-step body of slack,
// and consumers of the oldest loads sit at the body top.
// Bit-exactness: branchless charge via fmaf(h, ind, v) with ind in {0,1}
// (product exact); IEEE div for /3.0; reciprocal-mul for /80000 (absmax 0.0
// in rounds 1-2); unmasked reset select == reference semantics.

#pragma clang fp contract(off)

constexpr int T_TOTAL = 4000;
constexpr int NCH = 32;
constexpr int N1 = 64;
constexpr int N2 = 128;
constexpr int CT = 64;
constexpr int XSS = NCH + 1;

template <int CTRL>
__device__ __forceinline__ float dpp_max(float v) {
  int iv = __builtin_bit_cast(int, v);
  // old=self, bound_ctrl=false: invalid source lanes keep old value -> exact.
  int sh = __builtin_amdgcn_update_dpp(iv, iv, CTRL, 0xF, 0xF, false);
  return fmaxf(v, __builtin_bit_cast(float, sh));
}
__device__ __forceinline__ float read_lane_f(float v, int lane) {
  return __builtin_bit_cast(float, __builtin_amdgcn_readlane(__builtin_bit_cast(int, v), lane));
}

__global__ __launch_bounds__(64, 1) void lsm_kernel(
    const float* __restrict__ x, const float* __restrict__ W1,
    const float* __restrict__ W2, float* __restrict__ out) {
  __shared__ float w1s[N1 * 33];   // stride 33: column gather conflict-free
  __shared__ float w2s[N2 * 65];   // stride 65
  __shared__ float xs[CT * XSS];   // transposed x chunk: xs[t][c]

  const int lane = threadIdx.x;
  const int b = blockIdx.x;

  // Stage weights (single wave: in-wave DS ordering, no barrier needed).
  for (int e = lane; e < N1 * NCH; e += 64) w1s[(e >> 5) * 33 + (e & 31)] = W1[e];
  for (int e = lane; e < N2 * N1; e += 64) w2s[(e >> 6) * 65 + (e & 63)] = W2[e];

  const float* xb = x + (size_t)b * (NCH * T_TOTAL);

  // Lanes 32-63 mirror lanes 0-31 for L0 (xt indexed lane&31): identical
  // values, so the 32-lane reduce (readlane 31) and ballot-ffs (lowest lane)
  // are unaffected.
  float v0 = 0.f, d0 = 0.f, v1 = 0.f, v2a = 0.f, v2b = 0.f;
  float pv2a = 0.f, pv2b = 0.f;
  // Pipeline registers: produced body k, consumed body k+1 (same slot).
  float h1A = 0.f, i0A = 0.f, h1B = 0.f, i0B = 0.f;          // L0 -> L1
  float h2Aa = 0.f, h2Ab = 0.f, i1A = 0.f;                   // L1 -> L2
  float h2Ba = 0.f, h2Bb = 0.f, i1B = 0.f;

  const int w1base = lane * 33;
  const int w2ba = lane * 65;
  const int w2bb = (lane + 64) * 65;
  const int xlane = lane & 31;

  float xpre[NCH];
#pragma unroll
  for (int k = 0; k < NCH; ++k) xpre[k] = xb[k * T_TOTAL + lane];

  auto l2_step = [&](float h2a_, float h2b_, float i1_) {
    float pa = __builtin_fmaf(h2a_, i1_, v2a) - v2a * (1.0f / 80000.0f);
    float pb = __builtin_fmaf(h2b_, i1_, v2b) - v2b * (1.0f / 80000.0f);
    pv2a = pa; pv2b = pb;                  // only final assignment survives
    v2a = (pa >= 1.2f) ? 0.f : pa;         // unmasked reset == reference
    v2b = (pb >= 1.2f) ? 0.f : pb;
  };

  auto l1_step = [&](float h1_, float i0_, float& h2a_o, float& h2b_o, float& i1_o) {
    float nv1 = __builtin_fmaf(h1_, i0_, v1) - v1 * (1.0f / 80000.0f);
    v1 = (nv1 >= 1.2f) ? 0.f : nv1;
    float n = nv1;
    n = dpp_max<0x111>(n); n = dpp_max<0x112>(n); n = dpp_max<0x114>(n);
    n = dpp_max<0x118>(n); n = dpp_max<0x142>(n); n = dpp_max<0x143>(n);
    float m1 = read_lane_f(n, 63);
    i1_o = (m1 >= 1.2f) ? 1.0f : 0.0f;
    unsigned long long bal = __ballot(nv1 == m1);
    int j1 = __ffsll(bal) - 1;             // first-index tie-break == argmax
    h2a_o = w2s[w2ba + j1];                // consumed next body's L2
    h2b_o = w2s[w2bb + j1];
  };

  auto l0_step = [&](float xt, float& h1_o, float& i0_o) {
    float nv0 = (v0 + xt) - d0;
    float dn = nv0 / 3.0f;                 // IEEE div, issued off the select
    bool r = nv0 >= 1.5f;
    v0 = r ? 0.f : nv0;
    d0 = r ? 0.f : dn;                     // == v0_new / 3 (0/3 = +0 exact)
    float m = nv0;
    m = dpp_max<0x111>(m); m = dpp_max<0x112>(m); m = dpp_max<0x114>(m);
    m = dpp_max<0x118>(m); m = dpp_max<0x142>(m);
    float m0 = read_lane_f(m, 31);
    i0_o = (m0 >= 1.5f) ? 1.0f : 0.0f;
    unsigned long long bal = __ballot(nv0 == m0);
    int j0 = __ffsll(bal) - 1;             // lowest lane -> always < 32
    h1_o = w1s[w1base + j0];               // consumed next body's L1
  };

  const int nchunks = (T_TOTAL + CT - 1) / CT;  // 63 (last chunk: 32 steps)
  for (int c0 = 0; c0 < nchunks; ++c0) {
#pragma unroll
    for (int k = 0; k < NCH; ++k) xs[lane * XSS + k] = xpre[k];
    const int t0n = (c0 + 1) * CT;
    if (t0n < T_TOTAL) {
      const int tg = t0n + lane;
      const bool ok = tg < T_TOTAL;
#pragma unroll
      for (int k = 0; k < NCH; ++k) xpre[k] = ok ? xb[k * T_TOTAL + tg] : 0.f;
    }
    const int steps = min(CT, T_TOTAL - c0 * CT);  // 64 or 32 (even)
    float xtA = xs[xlane];                 // fresh rows 0,1 (overwrites any
    float xtB = xs[XSS + xlane];           //  stale tail prefetch)
    for (int tt = 0; tt < steps; tt += 2) {
      // Prefetch next body's inputs a full body early. &63 keeps the row
      // in-bounds; tail garbage is reloaded at the next chunk start.
      float xA_n = xs[((tt + 2) & 63) * XSS + xlane];
      float xB_n = xs[((tt + 3) & 63) * XSS + xlane];
      // L2: times t-4, t-3 (oldest hand-offs first)
      l2_step(h2Aa, h2Ab, i1A);
      l2_step(h2Ba, h2Bb, i1B);
      // L1: times t-2, t-1 (consume h1* before L0 overwrites; produce h2*)
      l1_step(h1A, i0A, h2Aa, h2Ab, i1A);
      l1_step(h1B, i0B, h2Ba, h2Bb, i1B);
      // L0: times t, t+1 (produce h1*, i0*)
      l0_step(xtA, h1A, i0A);
      l0_step(xtB, h1B, i0B);
      xtA = xA_n; xtB = xB_n;
    }
  }
  // Drain: L2 to 3997, then L1(3998)/L2(3998), L1(3999)/L2(3999).
  l2_step(h2Aa, h2Ab, i1A);                // 3996
  l2_step(h2Ba, h2Bb, i1B);                // 3997
  l1_step(h1A, i0A, h2Aa, h2Ab, i1A);      // 3998
  l2_step(h2Aa, h2Ab, i1A);                // 3998
  l1_step(h1B, i0B, h2Ba, h2Bb, i1B);      // 3999
  l2_step(h2Ba, h2Bb, i1B);                // 3999 -> final pv2
  out[(size_t)b * N2 + lane] = expf(pv2a);
  out[(size_t)b * N2 + 64 + lane] = expf(pv2b);
}

extern "C" void kernel_launch(void* const* d_in, const int* in_sizes, int n_in,
                              void* d_out, int out_size, void* d_ws, size_t ws_size,
                              hipStream_t stream) {
  (void)n_in; (void)out_size; (void)d_ws; (void)ws_size;
  const float* x = (const float*)d_in[0];
  const float* W1 = (const float*)d_in[1];
  const float* W2 = (const float*)d_in[2];
  float* out = (float*)d_out;
  const int B = in_sizes[0] / (NCH * T_TOTAL);  // 256
  lsm_kernel<<<dim3(B), dim3(64), 0, stream>>>(x, W1, W2, out);
}

// Round 4
// 872.199 us; speedup vs baseline: 1.7351x; 1.1629x over previous
//
#include <hip/hip_runtime.h>
#include <cstdint>
#include <cstddef>

// EEG_SimpleLSM round 4: wave-specialized pipeline.
// R3 evidence: single wave saturates at ~33% issue duty (DPP hazards, VALU<->SALU
// round-trips, lgkm waits) -> more same-wave ILP is dead. Instead: block=256,
// one wave per pipeline stage, skewed by one 64-step chunk:
//   phase p: wave3 stages x chunk p (global->LDS);  wave0 runs L0 on chunk p-1;
//            wave1 runs L1 on chunk p-2;            wave2 runs L2 on chunk p-3.
// Hand-offs: per step one packed scalar (spike<<8 | argmax) in double-buffered
// LDS rings, written as one ds_write per wave per chunk (per-lane accumulate,
// lane t holds step t's value), read as one ds_read + per-step readlane.
// Every cross-wave value is produced a full chunk (64 steps) early -> gathers
// and readlanes prefetch with a depth-2 rotation, zero chain exposure.
// Arithmetic identical to rounds 1-3 (absmax 0.0): IEEE div for /3, fmaf
// charge with flag in {0,1} (exact), reciprocal-mul for /80000, unmasked reset.

#pragma clang fp contract(off)

constexpr int T_TOTAL = 4000;
constexpr int NCH = 32;
constexpr int N1 = 64;
constexpr int N2 = 128;
constexpr int CT = 64;
constexpr int XSS = NCH + 1;                      // 33: conflict-free columns
constexpr int NCHUNK = (T_TOTAL + CT - 1) / CT;   // 63 (last chunk = 32 steps)

template <int CTRL>
__device__ __forceinline__ float dpp_max(float v) {
  int iv = __builtin_bit_cast(int, v);
  // old=self, bound_ctrl=false: invalid source lanes keep old value -> exact.
  int sh = __builtin_amdgcn_update_dpp(iv, iv, CTRL, 0xF, 0xF, false);
  return fmaxf(v, __builtin_bit_cast(float, sh));
}
__device__ __forceinline__ float read_lane_f(float v, int l) {
  return __builtin_bit_cast(float, __builtin_amdgcn_readlane(__builtin_bit_cast(int, v), l));
}
__device__ __forceinline__ int read_lane_i(int v, int l) {
  return __builtin_amdgcn_readlane(v, l);
}

__global__ __launch_bounds__(256, 1) void lsm_kernel(
    const float* __restrict__ x, const float* __restrict__ W1,
    const float* __restrict__ W2, float* __restrict__ out) {
  __shared__ float w1s[N1 * 33];        // W1[n][k] at n*33+k (2-way alias: free)
  __shared__ float w2s[N2 * 65];        // W2[n][k] at n*65+k
  __shared__ float xs[2][CT * XSS];     // x chunks, xs[t][c]
  __shared__ unsigned j0r[2][CT];       // L0->L1 ring: (spike<<8)|argmax per step
  __shared__ unsigned j1r[2][CT];       // L1->L2 ring

  const int tid = threadIdx.x;
  const int wid = tid >> 6;
  const int lane = tid & 63;
  const int b = blockIdx.x;

  for (int e = tid; e < N1 * NCH; e += 256) w1s[(e >> 5) * 33 + (e & 31)] = W1[e];
  for (int e = tid; e < N2 * N1; e += 256) w2s[(e >> 6) * 65 + (e & 63)] = W2[e];
  __syncthreads();

  const float* xb = x + (size_t)b * (NCH * T_TOTAL);

  // Persistent per-wave state (unused regs in other waves are harmless).
  float v0 = 0.f, d0 = 0.f;                         // wave0
  float v1 = 0.f;                                   // wave1
  float v2a = 0.f, v2b = 0.f, pv2a = 0.f, pv2b = 0.f;  // wave2

  for (int p = 0; p < NCHUNK + 3; ++p) {
    if (wid == 3) {
      // ---- stage x chunk p: global -> LDS, transposed ----
      const int c = p;
      if (c < NCHUNK) {
        float* dst = xs[c & 1];
        const int tg = c * CT + lane;
        const bool ok = tg < T_TOTAL;
#pragma unroll
        for (int k = 0; k < NCH; ++k)
          dst[lane * XSS + k] = ok ? xb[k * T_TOTAL + tg] : 0.f;
      }
    } else if (wid == 0) {
      // ---- L0 on chunk p-1 ----
      const int c = p - 1;
      if (c >= 0 && c < NCHUNK) {
        const float* xsb = xs[c & 1];
        const int S = min(CT, T_TOTAL - c * CT);
        const int xl = lane & 31;  // lanes 32-63 mirror 0-31 (reduce reads 31,
                                   // ffs picks the true low lane)
        unsigned jacc = 0u;
        float xc = xsb[xl];
        float xn = xsb[min(1, S - 1) * XSS + xl];
        for (int tt = 0; tt < S; ++tt) {
          float xf = xsb[min(tt + 2, S - 1) * XSS + xl];  // depth-2 prefetch
          float nv0 = (v0 + xc) - d0;
          float dn = nv0 / 3.0f;            // IEEE div == reference
          bool r = nv0 >= 1.5f;
          v0 = r ? 0.f : nv0;
          d0 = r ? 0.f : dn;                // == v0_new/3 (0/3 = +0 exact)
          float m = nv0;
          m = dpp_max<0x111>(m); m = dpp_max<0x112>(m); m = dpp_max<0x114>(m);
          m = dpp_max<0x118>(m); m = dpp_max<0x142>(m);
          float m0 = read_lane_f(m, 31);
          unsigned long long bal = __ballot(nv0 == m0);
          int j0 = __ffsll(bal) - 1;        // lowest lane == jnp.argmax tie-break
          unsigned packed = (unsigned)j0 | ((m0 >= 1.5f) ? 0x100u : 0u);
          jacc = (lane == tt) ? packed : jacc;  // packed is wave-uniform
          xc = xn; xn = xf;
        }
        j0r[c & 1][lane] = jacc;            // one write per chunk
      }
    } else if (wid == 1) {
      // ---- L1 on chunk p-2 ----
      const int c = p - 2;
      if (c >= 0 && c < NCHUNK) {
        const int S = min(CT, T_TOTAL - c * CT);
        const int jvi = (int)j0r[c & 1][lane];
        const int base1 = lane * 33;
        int pk0 = read_lane_i(jvi, 0);
        int pk1 = read_lane_i(jvi, min(1, S - 1));
        float h0 = w1s[base1 + (pk0 & 0xFF)];
        float hB = w1s[base1 + (pk1 & 0xFF)];
        float f0 = (pk0 & 0x100) ? 1.f : 0.f;
        float fB = (pk1 & 0x100) ? 1.f : 0.f;
        unsigned jacc = 0u;
        for (int tt = 0; tt < S; ++tt) {
          int pkn = read_lane_i(jvi, min(tt + 2, S - 1));
          float hn = w1s[base1 + (pkn & 0xFF)];     // depth-2 prefetch
          float fn = (pkn & 0x100) ? 1.f : 0.f;
          float nv1 = __builtin_fmaf(h0, f0, v1) - v1 * (1.0f / 80000.0f);
          v1 = (nv1 >= 1.2f) ? 0.f : nv1;           // unmasked reset
          float n = nv1;
          n = dpp_max<0x111>(n); n = dpp_max<0x112>(n); n = dpp_max<0x114>(n);
          n = dpp_max<0x118>(n); n = dpp_max<0x142>(n); n = dpp_max<0x143>(n);
          float m1 = read_lane_f(n, 63);
          unsigned long long bal = __ballot(nv1 == m1);
          int j1 = __ffsll(bal) - 1;
          unsigned packed = (unsigned)j1 | ((m1 >= 1.2f) ? 0x100u : 0u);
          jacc = (lane == tt) ? packed : jacc;
          h0 = hB; f0 = fB; hB = hn; fB = fn;
        }
        j1r[c & 1][lane] = jacc;
      }
    } else {
      // ---- L2 on chunk p-3 ----
      const int c = p - 3;
      if (c >= 0 && c < NCHUNK) {
        const int S = min(CT, T_TOTAL - c * CT);
        const int jvi = (int)j1r[c & 1][lane];
        const int ba = lane * 65;
        const int bb = (lane + 64) * 65;
        int pk0 = read_lane_i(jvi, 0);
        int pk1 = read_lane_i(jvi, min(1, S - 1));
        int j0_ = pk0 & 0xFF, j1_ = pk1 & 0xFF;
        float a0 = w2s[ba + j0_], b0 = w2s[bb + j0_];
        float aB = w2s[ba + j1_], bB = w2s[bb + j1_];
        float f0 = (pk0 & 0x100) ? 1.f : 0.f;
        float fB = (pk1 & 0x100) ? 1.f : 0.f;
        for (int tt = 0; tt < S; ++tt) {
          int pkn = read_lane_i(jvi, min(tt + 2, S - 1));
          int jn = pkn & 0xFF;
          float an = w2s[ba + jn], bn = w2s[bb + jn];  // depth-2 prefetch
          float fn = (pkn & 0x100) ? 1.f : 0.f;
          float pa = __builtin_fmaf(a0, f0, v2a) - v2a * (1.0f / 80000.0f);
          float pb = __builtin_fmaf(b0, f0, v2b) - v2b * (1.0f / 80000.0f);
          pv2a = pa; pv2b = pb;
          v2a = (pa >= 1.2f) ? 0.f : pa;
          v2b = (pb >= 1.2f) ? 0.f : pb;
          a0 = aB; b0 = bB; f0 = fB; aB = an; bB = bn; fB = fn;
        }
      }
    }
    __syncthreads();  // wave-uniform branches: all 4 waves always arrive
  }

  if (wid == 2) {
    out[(size_t)b * N2 + lane] = expf(pv2a);
    out[(size_t)b * N2 + 64 + lane] = expf(pv2b);
  }
}

extern "C" void kernel_launch(void* const* d_in, const int* in_sizes, int n_in,
                              void* d_out, int out_size, void* d_ws, size_t ws_size,
                              hipStream_t stream) {
  (void)n_in; (void)out_size; (void)d_ws; (void)ws_size;
  const float* x = (const float*)d_in[0];
  const float* W1 = (const float*)d_in[1];
  const float* W2 = (const float*)d_in[2];
  float* out = (float*)d_out;
  const int B = in_sizes[0] / (NCH * T_TOTAL);  // 256
  lsm_kernel<<<dim3(B), dim3(256), 0, stream>>>(x, W1, W2, out);
}

// Round 5
// 626.353 us; speedup vs baseline: 2.4161x; 1.3925x over previous
//
#include <hip/hip_runtime.h>
#include <cstdint>
#include <cstddef>

// EEG_SimpleLSM round 5: micro-stage wave specialization.
// R4 evidence: slowest stage ~428 cyc/step because each step's argmax reduce
// (12 DPP + readlane + ballot + ffs, ~100+ cyc with hazard wait-states) ran
// same-step-serial, and L0's IEEE div (~40 cyc) sits on its carried chain.
// Fact: no layer's v-recurrence depends on its OWN reduce (reset is per-lane).
// So: update waves (pure carried chain) stream nv into LDS rings; reduce
// waves one phase later run per-step-independent reduces (pipelineable).
//   8 waves, pipeline depth 5, phases p = 0..NCHUNK+4:
//     w4 loader: x chunk p -> xs ring (transposed)
//     w0 L0u (chunk p-1): v0/d0 recurrence (div-bound), nv0 -> ring
//     w2 L0r (chunk p-2): WTA argmax, TWO steps/pass (lane halves, cross-half
//                         combine via ds_swizzle xor16 — row_bcast15 leaks
//                         lane31->32..47 so it can't do dual-32 reduces)
//     w3 L1u (chunk p-3): v1 recurrence (gathers W1 col via j0 ring), nv1 -> ring
//     w1/w5 L1rE/L1rO (chunk p-4): 64-lane argmax, even/odd steps
//     w6/w7 L2a/L2b (chunk p-5): v2 recurrence for output rows 0-63 / 64-127
//   SIMD pairing (wid&3): S0 {L0u, loader}, S1 {L1rE, L1rO}, S2 {L0r, L2a},
//   S3 {L1u, L2b} — heavy stages never share a SIMD.
// Arithmetic identical to rounds 1-4 (absmax 0.0): IEEE div for /3, fmaf
// charge with flag in {0,1} (exact), reciprocal-mul for /80000, unmasked
// per-lane reset, ffs-of-ballot tie-break == jnp.argmax.

#pragma clang fp contract(off)

constexpr int T_TOTAL = 4000;
constexpr int NCH = 32;
constexpr int N1 = 64;
constexpr int N2 = 128;
constexpr int CT = 64;
constexpr int XSS = NCH + 1;                      // 33: conflict-free
constexpr int NCHUNK = (T_TOTAL + CT - 1) / CT;   // 63 (last chunk = 32 steps)

template <int CTRL>
__device__ __forceinline__ float dpp_max(float v) {
  int iv = __builtin_bit_cast(int, v);
  // old=self, bound_ctrl=false: invalid source lanes keep old value -> exact.
  int sh = __builtin_amdgcn_update_dpp(iv, iv, CTRL, 0xF, 0xF, false);
  return fmaxf(v, __builtin_bit_cast(float, sh));
}
__device__ __forceinline__ float swz16_max(float v) {
  // combine lane with lane^16 (ds_swizzle stays within each 32-lane group)
  int iv = __builtin_bit_cast(int, v);
  int sw = __builtin_amdgcn_ds_swizzle(iv, 0x401F);  // xor=16, and=0x1F
  return fmaxf(v, __builtin_bit_cast(float, sw));
}
__device__ __forceinline__ float read_lane_f(float v, int l) {
  return __builtin_bit_cast(float, __builtin_amdgcn_readlane(__builtin_bit_cast(int, v), l));
}
__device__ __forceinline__ int read_lane_i(int v, int l) {
  return __builtin_amdgcn_readlane(v, l);
}

__global__ __launch_bounds__(512, 1) void lsm_kernel(
    const float* __restrict__ x, const float* __restrict__ W1,
    const float* __restrict__ W2, float* __restrict__ out) {
  __shared__ float w1s[N1 * 33];        // W1[n][k] at n*33+k
  __shared__ float w2s[N2 * 65];        // W2[n][k] at n*65+k
  __shared__ float xs[2][CT * XSS];     // x chunks, xs[t][c]
  __shared__ float nv0r[2][CT * 64];    // L0 nv ring (lanes 32-63 mirror 0-31)
  __shared__ float nv1r[2][CT * 64];    // L1 nv ring
  __shared__ unsigned j0r[2][CT];       // (spike<<8)|argmax per step
  __shared__ unsigned j1r[2][CT];

  const int tid = threadIdx.x;
  const int wid = tid >> 6;
  const int lane = tid & 63;
  const int b = blockIdx.x;

  for (int e = tid; e < N1 * NCH; e += 512) w1s[(e >> 5) * 33 + (e & 31)] = W1[e];
  for (int e = tid; e < N2 * N1; e += 512) w2s[(e >> 6) * 65 + (e & 63)] = W2[e];
  __syncthreads();

  const float* xb = x + (size_t)b * (NCH * T_TOTAL);

  // Persistent per-wave state.
  float v0 = 0.f, d0 = 0.f;          // w0
  float v1 = 0.f;                    // w3
  float v2 = 0.f, pv2 = 0.f;         // w6 (rows 0-63) / w7 (rows 64-127)

  for (int p = 0; p < NCHUNK + 5; ++p) {
    if (wid == 4) {
      // ---------- loader: x chunk p -> xs, transposed ----------
      const int c = p;
      if (c < NCHUNK) {
        float* dst = xs[c & 1];
        const int tg = c * CT + lane;
        const bool ok = tg < T_TOTAL;
#pragma unroll
        for (int k = 0; k < NCH; ++k)
          dst[lane * XSS + k] = ok ? xb[k * T_TOTAL + tg] : 0.f;
      }
    } else if (wid == 0) {
      // ---------- L0 update (chunk p-1): div-bound carried chain ----------
      const int c = p - 1;
      if (c >= 0 && c < NCHUNK) {
        const float* xsb = xs[c & 1];
        float* nvd = nv0r[c & 1];
        const int S = min(CT, T_TOTAL - c * CT);
        const int xl = lane & 31;       // lanes 32-63 mirror 0-31
        float xc = xsb[xl];
        float xn = xsb[XSS + xl];       // S >= 32 so rows 0,1 exist
        for (int tt = 0; tt < S; ++tt) {
          float xf = xsb[min(tt + 2, S - 1) * XSS + xl];
          float nv0 = (v0 + xc) - d0;
          float dn = nv0 / 3.0f;        // IEEE div == reference
          bool r = nv0 >= 1.5f;
          v0 = r ? 0.f : nv0;
          d0 = r ? 0.f : dn;            // == v0_new/3 (0/3 = +0 exact)
          nvd[tt * 64 + lane] = nv0;    // off-chain stream-out
          xc = xn; xn = xf;
        }
      }
    } else if (wid == 2) {
      // ---------- L0 reduce (chunk p-2): two steps per pass ----------
      const int c = p - 2;
      if (c >= 0 && c < NCHUNK) {
        const float* nvs = nv0r[c & 1];
        const int S = min(CT, T_TOTAL - c * CT);
        const int pairs = S >> 1;       // S even always
        // lanes 0-31: step 2i neurons 0-31; lanes 32-63: step 2i+1
        const int lbase = ((lane & 32) << 1) + (lane & 31);
        unsigned jacc = 0u;
        const bool hi = lane >= 32;
#pragma unroll 2
        for (int i = 0; i < pairs; ++i) {
          float nv = nvs[128 * i + lbase];
          float m = nv;
          m = dpp_max<0x111>(m); m = dpp_max<0x112>(m);
          m = dpp_max<0x114>(m); m = dpp_max<0x118>(m);
          m = swz16_max(m);             // rows 0+1 -> lane31; rows 2+3 -> lane63
          float mA = read_lane_f(m, 31);
          float mB = read_lane_f(m, 63);
          float mbc = hi ? mB : mA;
          unsigned long long bal = __ballot(nv == mbc);
          int jA = __ffsll(bal & 0xFFFFFFFFull) - 1;   // lowest neuron == argmax
          int jB = __ffsll(bal >> 32) - 1;
          unsigned pkA = (unsigned)jA | ((mA >= 1.5f) ? 0x100u : 0u);
          unsigned pkB = (unsigned)jB | ((mB >= 1.5f) ? 0x100u : 0u);
          jacc = (lane == 2 * i) ? pkA : jacc;
          jacc = (lane == 2 * i + 1) ? pkB : jacc;
        }
        j0r[c & 1][lane] = jacc;
      }
    } else if (wid == 3) {
      // ---------- L1 update (chunk p-3): short carried chain ----------
      const int c = p - 3;
      if (c >= 0 && c < NCHUNK) {
        const int S = min(CT, T_TOTAL - c * CT);
        const int jv = (int)j0r[c & 1][lane];
        float* nvd = nv1r[c & 1];
        const int base1 = lane * 33;
        int pk0 = read_lane_i(jv, 0);
        int pk1 = read_lane_i(jv, 1);
        float h0 = w1s[base1 + (pk0 & 0xFF)];
        float hB = w1s[base1 + (pk1 & 0xFF)];
        float f0 = (pk0 & 0x100) ? 1.f : 0.f;
        float fB = (pk1 & 0x100) ? 1.f : 0.f;
        for (int tt = 0; tt < S; ++tt) {
          int pkn = read_lane_i(jv, min(tt + 2, S - 1));
          float hn = w1s[base1 + (pkn & 0xFF)];   // depth-2 prefetch
          float fn = (pkn & 0x100) ? 1.f : 0.f;
          float nv1 = __builtin_fmaf(h0, f0, v1) - v1 * (1.0f / 80000.0f);
          v1 = (nv1 >= 1.2f) ? 0.f : nv1;         // per-lane unmasked reset
          nvd[tt * 64 + lane] = nv1;              // off-chain stream-out
          h0 = hB; f0 = fB; hB = hn; fB = fn;
        }
      }
    } else if (wid == 1 || wid == 5) {
      // ---------- L1 reduce (chunk p-4): even (w1) / odd (w5) steps ----------
      const int c = p - 4;
      if (c >= 0 && c < NCHUNK) {
        const int q = (wid == 1) ? 0 : 1;
        const float* nvs = nv1r[c & 1];
        const int S = min(CT, T_TOTAL - c * CT);
        unsigned jacc = 0u;
#pragma unroll 2
        for (int tt = q; tt < S; tt += 2) {
          float nv = nvs[tt * 64 + lane];
          float m = nv;
          m = dpp_max<0x111>(m); m = dpp_max<0x112>(m); m = dpp_max<0x114>(m);
          m = dpp_max<0x118>(m); m = dpp_max<0x142>(m); m = dpp_max<0x143>(m);
          float m1 = read_lane_f(m, 63);
          unsigned long long bal = __ballot(nv == m1);
          int j1 = __ffsll(bal) - 1;
          unsigned pk = (unsigned)j1 | ((m1 >= 1.2f) ? 0x100u : 0u);
          jacc = (lane == tt) ? pk : jacc;
        }
        if ((lane & 1) == q) j1r[c & 1][lane] = jacc;  // own-parity lanes only
      }
    } else {
      // ---------- L2 update (chunk p-5): w6 rows 0-63, w7 rows 64-127 ----------
      const int c = p - 5;
      if (c >= 0 && c < NCHUNK) {
        const int S = min(CT, T_TOTAL - c * CT);
        const int jv = (int)j1r[c & 1][lane];
        const int wbase = (lane + ((wid == 7) ? 64 : 0)) * 65;
        int pk0 = read_lane_i(jv, 0);
        int pk1 = read_lane_i(jv, 1);
        float h0 = w2s[wbase + (pk0 & 0xFF)];
        float hB = w2s[wbase + (pk1 & 0xFF)];
        float f0 = (pk0 & 0x100) ? 1.f : 0.f;
        float fB = (pk1 & 0x100) ? 1.f : 0.f;
        for (int tt = 0; tt < S; ++tt) {
          int pkn = read_lane_i(jv, min(tt + 2, S - 1));
          float hn = w2s[wbase + (pkn & 0xFF)];   // depth-2 prefetch
          float fn = (pkn & 0x100) ? 1.f : 0.f;
          float nv2 = __builtin_fmaf(h0, f0, v2) - v2 * (1.0f / 80000.0f);
          pv2 = nv2;                               // pre-reset membrane
          v2 = (nv2 >= 1.2f) ? 0.f : nv2;
          h0 = hB; f0 = fB; hB = hn; fB = fn;
        }
      }
    }
    __syncthreads();  // wid branches are wave-uniform: all 8 waves arrive
  }

  if (wid == 6) out[(size_t)b * N2 + lane] = expf(pv2);
  if (wid == 7) out[(size_t)b * N2 + 64 + lane] = expf(pv2);
}

extern "C" void kernel_launch(void* const* d_in, const int* in_sizes, int n_in,
                              void* d_out, int out_size, void* d_ws, size_t ws_size,
                              hipStream_t stream) {
  (void)n_in; (void)out_size; (void)d_ws; (void)ws_size;
  const float* x = (const float*)d_in[0];
  const float* W1 = (const float*)d_in[1];
  const float* W2 = (const float*)d_in[2];
  float* out = (float*)d_out;
  const int B = in_sizes[0] / (NCH * T_TOTAL);  // 256
  lsm_kernel<<<dim3(B), dim3(512), 0, stream>>>(x, W1, W2, out);
}

// Round 6
// 615.240 us; speedup vs baseline: 2.4597x; 1.0181x over previous
//
#include <hip/hip_runtime.h>
#include <cstdint>
#include <cstddef>

// EEG_SimpleLSM round 6: transposed reduces + depth-8 prefetch + div-free L0.
// R5 evidence: slowest stage ~274 cyc/step — per-step DPP/ds reduce chains
// (~300 cyc each, never pipelined by the compiler) and depth-2 prefetches
// leaving ~90 cyc of ds_read latency exposed per step.
// Fixes:
//  (1) Argmax by transpose: reduce wave takes lane=step, scans neurons from
//      the [step][neuron] ring (stride 33/65 -> 2-way bank alias = free) with
//      v>m ? (m=v,j=n): first-index tie-break == jnp.argmax. No DPP, no
//      ballot, no readlane; all 64 steps reduce in one independent-issue pass.
//      L1's 64-neuron scan splits across two waves (neuron halves); L2 merges
//      the partials per-lane (tie prefers low half = first index).
//  (2) Depth-8 register rotation (unroll-8) for x reads and W-column gathers:
//      slack ~8 steps >= ~120-cyc LDS latency. S in {64,32}, both %8==0.
//  (3) L0's /3.0 via exact f64 multiply: dn=(float)((double)nv0*(1.0/3.0)).
//      Proof: f64 rel err <= 2^-52.4; a 24-bit quotient by 3 is never within
//      2^-27 (rel) of an f32 breakpoint unless exact -> double rounding is
//      identical to IEEE f32 divide. Carried chain ~60 -> ~24 cyc/step.
// Waves (512 thr): w6 loader(p) | w0 L0u(p-1) | w1 L0r(p-2) | w2 L1u(p-3) |
// w3/w7 L1r lo/hi(p-4) | w4/w5 L2 rows 0-63/64-127 (p-5). Depth-5 pipeline,
// double-buffered rings, one __syncthreads per phase (wave-uniform branches).
// Arithmetic identical to rounds 1-5 (absmax 0.0): fmaf charge with flag in
// {0,1} (exact), reciprocal-mul for /80000, unmasked per-lane reset.

#pragma clang fp contract(off)

constexpr int T_TOTAL = 4000;
constexpr int NCH = 32;
constexpr int N1 = 64;
constexpr int N2 = 128;
constexpr int CT = 64;
constexpr int XSS = NCH + 1;                      // 33
constexpr int NCHUNK = (T_TOTAL + CT - 1) / CT;   // 63 (last chunk = 32 steps)

__device__ __forceinline__ int read_lane_i(int v, int l) {
  return __builtin_amdgcn_readlane(v, l);
}

__global__ __launch_bounds__(512, 1) void lsm_kernel(
    const float* __restrict__ x, const float* __restrict__ W1,
    const float* __restrict__ W2, float* __restrict__ out) {
  __shared__ float w1s[N1 * 33];        // W1[n][k] at n*33+k
  __shared__ float w2s[N2 * 65];        // W2[n][k] at n*65+k
  __shared__ float xs[2][CT * XSS];     // x chunk, [time][ch], stride 33
  __shared__ float nv0r[2][CT * 33];    // L0 nv ring, [step][neuron<32]
  __shared__ float nv1r[2][CT * 65];    // L1 nv ring, [step][neuron<64]
  __shared__ unsigned j0r[2][CT];       // L0 (spike<<8)|argmax per step
  __shared__ float mpr[2][2][CT];       // L1 partial max  [parity][half][step]
  __shared__ int   jpr[2][2][CT];       // L1 partial argj [parity][half][step]

  const int tid = threadIdx.x;
  const int wid = tid >> 6;
  const int lane = tid & 63;
  const int b = blockIdx.x;

  for (int e = tid; e < N1 * NCH; e += 512) w1s[(e >> 5) * 33 + (e & 31)] = W1[e];
  for (int e = tid; e < N2 * N1; e += 512) w2s[(e >> 6) * 65 + (e & 63)] = W2[e];
  __syncthreads();

  const float* xb = x + (size_t)b * (NCH * T_TOTAL);

  // Persistent per-wave state.
  float v0 = 0.f, d0 = 0.f;          // w0
  float v1 = 0.f;                    // w2
  float v2 = 0.f, pv2 = 0.f;         // w4 (rows 0-63) / w5 (rows 64-127)

  for (int p = 0; p < NCHUNK + 5; ++p) {
    if (wid == 6) {
      // ---------- loader: x chunk p -> xs, transposed ----------
      const int c = p;
      if (c < NCHUNK) {
        float* dst = xs[c & 1];
        const int tg = c * CT + lane;
        const bool ok = tg < T_TOTAL;
#pragma unroll
        for (int k = 0; k < NCH; ++k)
          dst[lane * XSS + k] = ok ? xb[k * T_TOTAL + tg] : 0.f;
      }
    } else if (wid == 0) {
      // ---------- L0 update (chunk p-1): the wall — carried chain ----------
      const int c = p - 1;
      if (c >= 0 && c < NCHUNK) {
        const float* xsb = xs[c & 1];
        float* nvd = nv0r[c & 1];
        const int S = min(CT, T_TOTAL - c * CT);
        const int xl = lane & 31;       // lanes 32-63 mirror 0-31 (same-value
                                        // dup LDS writes: harmless, 2-way)
        float xr[8];
#pragma unroll
        for (int k = 0; k < 8; ++k) xr[k] = xsb[k * XSS + xl];
        for (int tb = 0; tb < S; tb += 8) {
#pragma unroll
          for (int k = 0; k < 8; ++k) {
            const int tt = tb + k;
            float xc = xr[k];
            int tn = tt + 8; tn = (tn < S) ? tn : S - 1;   // depth-8 prefetch
            xr[k] = xsb[tn * XSS + xl];
            float nv0 = (v0 + xc) - d0;
            double q = (double)nv0 * (1.0 / 3.0);
            float dn = (float)q;        // == RN32(nv0/3) — see header proof
            bool r = nv0 >= 1.5f;
            v0 = r ? 0.f : nv0;
            d0 = r ? 0.f : dn;          // 0/3 = +0 exact
            nvd[tt * 33 + xl] = nv0;    // off-chain stream-out
          }
        }
      }
    } else if (wid == 1) {
      // ---------- L0 reduce (chunk p-2): lane = step, scan 32 neurons ----
      const int c = p - 2;
      if (c >= 0 && c < NCHUNK) {
        const float* nvs = nv0r[c & 1] + lane * 33;
        float m = nvs[0];
        int j = 0;
#pragma unroll 8
        for (int n = 1; n < 32; ++n) {
          float v = nvs[n];
          bool g = v > m;               // strict: first index kept on ties
          j = g ? n : j;
          m = g ? v : m;
        }
        // lanes >= S hold garbage from stale ring rows: finite, never read.
        j0r[c & 1][lane] = (unsigned)j | ((m >= 1.5f) ? 0x100u : 0u);
      }
    } else if (wid == 2) {
      // ---------- L1 update (chunk p-3) ----------
      const int c = p - 3;
      if (c >= 0 && c < NCHUNK) {
        const int S = min(CT, T_TOTAL - c * CT);
        const int jv = (int)j0r[c & 1][lane];
        float* nvd = nv1r[c & 1];
        const int base1 = lane * 33;
        float hr[8], fr[8];
#pragma unroll
        for (int k = 0; k < 8; ++k) {
          int pk = read_lane_i(jv, k);
          hr[k] = w1s[base1 + (pk & 0xFF)];
          fr[k] = (pk & 0x100) ? 1.f : 0.f;
        }
        for (int tb = 0; tb < S; tb += 8) {
#pragma unroll
          for (int k = 0; k < 8; ++k) {
            const int tt = tb + k;
            float h = hr[k], f = fr[k];
            int tn = tt + 8; tn = (tn < S) ? tn : S - 1;   // depth-8 prefetch
            int pk = read_lane_i(jv, tn);
            hr[k] = w1s[base1 + (pk & 0xFF)];
            fr[k] = (pk & 0x100) ? 1.f : 0.f;
            float nv1 = __builtin_fmaf(h, f, v1) - v1 * (1.0f / 80000.0f);
            v1 = (nv1 >= 1.2f) ? 0.f : nv1;   // per-lane unmasked reset
            nvd[tt * 65 + lane] = nv1;
          }
        }
      }
    } else if (wid == 3 || wid == 7) {
      // ---------- L1 reduce (chunk p-4): lane = step, neuron half-scan ----
      const int c = p - 4;
      if (c >= 0 && c < NCHUNK) {
        const int half = (wid == 7) ? 1 : 0;
        const float* nvs = nv1r[c & 1] + lane * 65 + half * 32;
        float m = nvs[0];
        int j = 0;
#pragma unroll 8
        for (int n = 1; n < 32; ++n) {
          float v = nvs[n];
          bool g = v > m;
          j = g ? n : j;
          m = g ? v : m;
        }
        mpr[c & 1][half][lane] = m;
        jpr[c & 1][half][lane] = j;
      }
    } else {
      // ---------- L2 update (chunk p-5): w4 rows 0-63, w5 rows 64-127 ----
      const int c = p - 5;
      if (c >= 0 && c < NCHUNK) {
        const int S = min(CT, T_TOTAL - c * CT);
        // merge L1 partials per-lane (lane = step); tie -> low half = first idx
        float mlo = mpr[c & 1][0][lane], mhi = mpr[c & 1][1][lane];
        int jlo = jpr[c & 1][0][lane], jhi = jpr[c & 1][1][lane];
        bool g = mhi > mlo;
        float mm = g ? mhi : mlo;
        int jj = g ? (jhi + 32) : jlo;
        const int pkv = jj | ((mm >= 1.2f) ? 0x100 : 0);
        const int wbase = (lane + ((wid == 5) ? 64 : 0)) * 65;
        float hr[8], fr[8];
#pragma unroll
        for (int k = 0; k < 8; ++k) {
          int pk = read_lane_i(pkv, k);
          hr[k] = w2s[wbase + (pk & 0xFF)];
          fr[k] = (pk & 0x100) ? 1.f : 0.f;
        }
        for (int tb = 0; tb < S; tb += 8) {
#pragma unroll
          for (int k = 0; k < 8; ++k) {
            const int tt = tb + k;
            float h = hr[k], f = fr[k];
            int tn = tt + 8; tn = (tn < S) ? tn : S - 1;   // depth-8 prefetch
            int pk = read_lane_i(pkv, tn);
            hr[k] = w2s[wbase + (pk & 0xFF)];
            fr[k] = (pk & 0x100) ? 1.f : 0.f;
            float nv2 = __builtin_fmaf(h, f, v2) - v2 * (1.0f / 80000.0f);
            pv2 = nv2;                  // pre-reset membrane
            v2 = (nv2 >= 1.2f) ? 0.f : nv2;
          }
        }
      }
    }
    __syncthreads();  // wave-uniform branches: all 8 waves always arrive
  }

  if (wid == 4) out[(size_t)b * N2 + lane] = expf(pv2);
  if (wid == 5) out[(size_t)b * N2 + 64 + lane] = expf(pv2);
}

extern "C" void kernel_launch(void* const* d_in, const int* in_sizes, int n_in,
                              void* d_out, int out_size, void* d_ws, size_t ws_size,
                              hipStream_t stream) {
  (void)n_in; (void)out_size; (void)d_ws; (void)ws_size;
  const float* x = (const float*)d_in[0];
  const float* W1 = (const float*)d_in[1];
  const float* W2 = (const float*)d_in[2];
  float* out = (float*)d_out;
  const int B = in_sizes[0] / (NCH * T_TOTAL);  // 256
  lsm_kernel<<<dim3(B), dim3(512), 0, stream>>>(x, W1, W2, out);
}